// Round 10
// baseline (258.071 us; speedup 1.0000x reference)
//
#include <hip/hip_runtime.h>
#include <hip/hip_bf16.h>

#define N_NODES 131072
#define DIM 128
#define NG 512

typedef __bf16 bf16;
typedef __attribute__((ext_vector_type(8))) __bf16 bf16x8;
typedef __attribute__((ext_vector_type(4))) float f32x4;

// 1/sqrt(128) * log2(e) — folded into Wk/bk so attention scores exp2 directly
#define KSC 0.12753785006196978f

// workspace layout (bytes)
#define WS_STARTS 0                         // 513 ints
#define WS_WF     8192                      // fragment-ordered W: 3*8*4*64*8 bf16 = 98304 B
#define WS_KB     131072                    // N*128 bf16
#define WS_QB     (131072 + 33554432)
#define WS_VTB    (131072 + 2*33554432)     // Vt[d][n]: 128 x N bf16

__device__ __forceinline__ void gl_lds16(const void* g, void* l) {
    __builtin_amdgcn_global_load_lds(
        (const __attribute__((address_space(1))) unsigned int*)g,
        (__attribute__((address_space(3))) unsigned int*)l, 16, 0, 0);
}

__global__ void seg_starts_kernel(const int* __restrict__ batch, int* __restrict__ starts) {
    int g = threadIdx.x;                    // 0..511
    int lo = 0, hi = N_NODES;
    while (lo < hi) { int mid = (lo + hi) >> 1; if (batch[mid] < g) lo = mid + 1; else hi = mid; }
    starts[g] = lo;
    if (g == 0) starts[NG] = N_NODES;
}

// Emit W in B-fragment order: Wf[((mat*8+n0)*4+ks)*64 + lane] is the bf16x8 that
// lane reads for MFMA (col = n0*16 + (lane&15), k = ks*32 + (lane>>4)*8 + j).
// Wk (mat 0) is pre-scaled by KSC so attention scores are exp2-ready.
__global__ void wconv_kernel(const float* __restrict__ Wk, const float* __restrict__ Wq,
                             const float* __restrict__ Wv, bf16* __restrict__ Wf) {
    int f = blockIdx.x * 256 + threadIdx.x;  // 0..6143
    int lane = f & 63, ks = (f >> 6) & 3, n0 = (f >> 8) & 7, mat = f >> 11;
    const float* src = (mat == 0) ? Wk : ((mat == 1) ? Wq : Wv);
    float sc = (mat == 0) ? KSC : 1.0f;
    int col = n0 * 16 + (lane & 15);
    int koff = ks * 32 + (lane >> 4) * 8;
    const float* p = src + col * DIM + koff;
    bf16* dst = Wf + (size_t)f * 8;
    #pragma unroll
    for (int j = 0; j < 8; j++) dst[j] = (bf16)(p[j] * sc);
}

// QKV projection: out = x @ W^T + b, stored bf16 (x read ONCE per block, 3 mats).
// V stored transposed: Vt[d][n]. All global stores 16B coalesced via LDS tile.
// R10: 512 threads / 8 waves per 128-row block (was 256/4). qkv is ~80us vs a
// 27us BW floor with exactly 4 blocks/CU of work and zero slack — same latency
// disease as attn. Per-wave work halves (one 16-row group), waves/CU double
// (16 -> 32) to hide Wf-load/store/barrier latency. LDS unchanged (4 blocks/CU).
__global__ __launch_bounds__(512) void qkv_kernel(
        const float* __restrict__ x, const bf16* __restrict__ Wf,
        const float* __restrict__ bk, const float* __restrict__ bq, const float* __restrict__ bv,
        bf16* __restrict__ Kb, bf16* __restrict__ Qb, bf16* __restrict__ Vtb) {
    __shared__ bf16 tile[128 * 136];         // 34816 B; x-tile first, then C-tile per mat
    const int tid = threadIdx.x;             // 0..511
    const int w = tid >> 6, lane = tid & 63, q = lane >> 4, i = lane & 15;
    const int r0 = blockIdx.x * 128;

    {   // stage x tile (coalesced fp32 loads -> bf16 LDS): 16384 elems, 8 iters
        #pragma unroll
        for (int it = 0; it < 8; it++) {
            int e = tid * 4 + it * 2048;     // element in 128x128 tile
            int row = e >> 7, col = e & 127;
            float4 u = *(const float4*)(x + (size_t)(r0 + row) * DIM + col);
            bf16 b[4] = {(bf16)u.x, (bf16)u.y, (bf16)u.z, (bf16)u.w};
            *(ushort4*)&tile[row * 136 + col] = *(ushort4*)b;
        }
    }
    __syncthreads();

    // A fragments from LDS: wave w owns rows r0 + w*16 + i (one 16-row group)
    bf16x8 af[4];
    #pragma unroll
    for (int ks = 0; ks < 4; ks++)
        af[ks] = *(const bf16x8*)&tile[(w * 16 + i) * 136 + ks * 32 + q * 8];
    __syncthreads();                         // frag reads done before tile reuse

    for (int mat = 0; mat < 3; mat++) {
        const float* bias = (mat == 0) ? bk : ((mat == 1) ? bq : bv);
        const float bscale = (mat == 0) ? KSC : 1.0f;
        for (int n0 = 0; n0 < 8; n0++) {
            int col = n0 * 16 + i;
            float bias_v = bias[col] * bscale;
            f32x4 acc = {0, 0, 0, 0};
            #pragma unroll
            for (int ks = 0; ks < 4; ks++) {
                bf16x8 bw = *(const bf16x8*)(Wf + ((size_t)((mat * 8 + n0) * 4 + ks) * 64 + lane) * 8);
                acc = __builtin_amdgcn_mfma_f32_16x16x32_bf16(af[ks], bw, acc, 0, 0, 0);
            }
            #pragma unroll
            for (int r = 0; r < 4; r++) {
                int rowl = w * 16 + q * 4 + r;
                bf16 hv = (bf16)(acc[r] + bias_v);
                if (mat < 2) tile[rowl * 136 + col] = hv;   // row-major [row][d]
                else         tile[col * 136 + rowl] = hv;   // transposed [d][row]
            }
        }
        __syncthreads();
        {   // coalesced stores: 512 thr, row = tid>>2, quarter (32 elems = 64B) each
            int row = tid >> 2, qtr = tid & 3;
            const uint4* src = (const uint4*)(tile + row * 136 + qtr * 32);
            uint4* dst;
            if (mat == 0)      dst = (uint4*)(Kb  + (size_t)(r0 + row) * DIM + qtr * 32);
            else if (mat == 1) dst = (uint4*)(Qb  + (size_t)(r0 + row) * DIM + qtr * 32);
            else               dst = (uint4*)(Vtb + (size_t)row * N_NODES + r0 + qtr * 32);
            #pragma unroll
            for (int j = 0; j < 4; j++) dst[j] = src[j];
        }
        __syncthreads();
    }
}

// Fused segment attention + residual + LayerNorm.
// R10: verbatim revert to R5's measured-best config (82us). R9 showed the
// grid (~1150 blocks ~= 4.5 blocks/CU of WORK) can't exploit >3 resident
// blocks: allowing 4-5 turns the kernel into one co-scheduled batch with a
// pure c-variance tail (occupancy fell 23 -> 16.5%, dur 82 -> 87). R5's
// LDS-limited 3 blocks/CU packs best. attn is plateaued in this structure.
__global__ __launch_bounds__(256, 3) void attn_kernel(
        const float* __restrict__ x,
        const bf16* __restrict__ Kb, const bf16* __restrict__ Qb, const bf16* __restrict__ Vtb,
        const float* __restrict__ gamma, const float* __restrict__ beta,
        const int* __restrict__ starts, float* __restrict__ out) {
    __shared__ bf16 Qs[3][32 * 128];         // 3 x 8192 B; P overlays Qs[cur]
    __shared__ bf16 Vts[3][128 * 32];        // 3 x 8192 B   (total 49152 B -> 3 blocks/CU)

    const int g = blockIdx.x;
    const int seg = starts[g];
    const int c = starts[g + 1] - seg;
    const int l0 = blockIdx.y * 128;
    if (l0 >= c) return;

    const int tid = threadIdx.x;
    const int w = tid >> 6, lane = tid & 63, q = lane >> 4, i = lane & 15;

    const int mstart = seg & ~7;             // 8-aligned -> 16B-aligned staging
    const int nch = (seg - mstart + c + 31) >> 5;   // 32-m chunks (>= 6 since c >= 192)

    // async-stage one 32-m chunk: Q rows (32x128) + Vt rows (128x32), swizzled source.
    // 4 gl_lds16 per wave (2 Q + 2 Vt); LDS dest wave-uniform base + lane*16B (linear).
    auto stage = [&](int buf, int mb) {
        #pragma unroll
        for (int p = 0; p < 2; p++) {        // Q: 1 instr = 4 rows (16 lanes/row)
            int row = w * 8 + p * 4 + (lane >> 4);
            int gr = mb + row; if (gr > N_NODES - 1) gr = N_NODES - 1;
            gl_lds16(Qb + (size_t)gr * DIM + (((lane & 15) ^ (row & 7)) << 3),
                     &Qs[buf][(w * 8 + p * 4) * 128]);
        }
        #pragma unroll
        for (int p = 0; p < 2; p++) {        // Vt: 1 instr = 16 rows (4 lanes/row)
            int d = w * 32 + p * 16 + (lane >> 2);
            int tvd = ((lane >> 2) ^ (lane >> 4)) & 3;       // = (d ^ (d>>2)) & 3
            int mo = mb + (((lane & 3) ^ tvd) << 3);
            if (mo > N_NODES - 8) mo = N_NODES - 8;
            gl_lds16(Vtb + (size_t)d * N_NODES + mo,
                     &Vts[buf][(w * 32 + p * 16) * 32]);
        }
    };

    // K fragments direct from global (row clamped into segment); 32 l-rows per wave
    bf16x8 afK[2][4];
    #pragma unroll
    for (int rg = 0; rg < 2; rg++) {
        int lrow = l0 + w * 32 + rg * 16 + i;
        if (lrow > c - 1) lrow = c - 1;
        const bf16* krow = Kb + (size_t)(seg + lrow) * DIM;
        #pragma unroll
        for (int ks = 0; ks < 4; ks++)
            afK[rg][ks] = *(const bf16x8*)(krow + ks * 32 + q * 8);
    }

    stage(0, mstart);                        // depth-2 pipeline prologue
    if (nch > 1) stage(1, mstart + 32);

    float li[2][4] = {{0,0,0,0},{0,0,0,0}};
    f32x4 Oc[2][8];
    #pragma unroll
    for (int rg = 0; rg < 2; rg++)
        #pragma unroll
        for (int t = 0; t < 8; t++) Oc[rg][t] = (f32x4){0,0,0,0};

    const int f7 = i & 7;                    // Q-read swizzle term (= row&7)
    const int tvi = (i ^ (i >> 2)) & 3;      // Vt/P read swizzle term

    for (int mc = 0; mc < nch; mc++) {
        const int cur = mc % 3;
        const int mbase = mstart + (mc << 5);
        // counted wait: retire chunk mc's 4 DMAs; chunk mc+1's 4 stay in flight
        if (mc + 1 < nch) asm volatile("s_waitcnt vmcnt(4)" ::: "memory");
        else              asm volatile("s_waitcnt vmcnt(0)" ::: "memory");
        __builtin_amdgcn_s_barrier();
        __builtin_amdgcn_sched_barrier(0);
        // buf (mc+2)%3 was fully consumed in iteration mc-1 (readers passed this barrier)
        if (mc + 2 < nch) stage((mc + 2) % 3, mbase + 64);

        const bf16* QsB = Qs[cur];
        const bf16* VtB = Vts[cur];
        bf16* Pw = &Qs[cur][w * 1024];       // wave-private 32x32 P slice (overlay)

        // S = K * Q^T (32 l-rows x 32 m-cols per wave): 8 bq reads feed 16 MFMAs
        f32x4 s[2][2];
        __builtin_amdgcn_s_setprio(1);
        #pragma unroll
        for (int ti = 0; ti < 2; ti++) {
            f32x4 a0 = {0,0,0,0}, a1 = {0,0,0,0};
            #pragma unroll
            for (int ks = 0; ks < 4; ks++) {
                bf16x8 bq = *(const bf16x8*)&QsB[(ti * 16 + i) * 128 + (((ks * 4 + q) ^ f7) << 3)];
                a0 = __builtin_amdgcn_mfma_f32_16x16x32_bf16(afK[0][ks], bq, a0, 0, 0, 0);
                a1 = __builtin_amdgcn_mfma_f32_16x16x32_bf16(afK[1][ks], bq, a1, 0, 0, 0);
            }
            s[0][ti] = a0; s[1][ti] = a1;
        }
        __builtin_amdgcn_s_setprio(0);
        if (mc == 0 || mc == nch - 1) {      // only edge chunks can have invalid m
            #pragma unroll
            for (int ti = 0; ti < 2; ti++) {
                int mg = mbase + ti * 16 + i;
                bool valid = (mg >= seg) && (mg < seg + c);
                if (!valid) {
                    s[0][ti] = (f32x4){-1.0e30f, -1.0e30f, -1.0e30f, -1.0e30f};
                    s[1][ti] = s[0][ti];
                }
            }
        }
        // p = exp2(s) in registers; accumulate l per-lane
        #pragma unroll
        for (int rg = 0; rg < 2; rg++)
            #pragma unroll
            for (int ti = 0; ti < 2; ti++)
                #pragma unroll
                for (int r = 0; r < 4; r++) {
                    float pv = exp2f(s[rg][ti][r]);
                    li[rg][r] += pv;
                    s[rg][ti][r] = pv;
                }

        // raw barrier: all waves' Qs[cur] reads retired; DMA (vmcnt) stays in flight
        asm volatile("s_waitcnt lgkmcnt(0)" ::: "memory");
        __builtin_amdgcn_s_barrier();
        __builtin_amdgcn_sched_barrier(0);

        // write P into overlay (rows = wave's 32 l-rows, cols = 32 m), swizzled:
        // slot = colgranule ^ (q^r)   [q^r == (row ^ row>>2)&3 for row=rg*16+q*4+r]
        #pragma unroll
        for (int rg = 0; rg < 2; rg++)
            #pragma unroll
            for (int ti = 0; ti < 2; ti++)
                #pragma unroll
                for (int r = 0; r < 4; r++) {
                    int rowl = rg * 16 + q * 4 + r;
                    int slot = (ti * 2 + (i >> 3)) ^ (q ^ r);
                    Pw[rowl * 32 + slot * 8 + f7] = (bf16)s[rg][ti][r];
                }

        // read P as A-fragments (same-wave LDS FIFO: no barrier needed)
        bf16x8 afP[2];
        #pragma unroll
        for (int rg = 0; rg < 2; rg++)
            afP[rg] = *(const bf16x8*)&Pw[(rg * 16 + i) * 32 + ((q ^ tvi) << 3)];

        // O += P * Vt: 8 bv reads feed 16 MFMAs
        __builtin_amdgcn_s_setprio(1);
        #pragma unroll
        for (int dt = 0; dt < 8; dt++) {
            bf16x8 bv = *(const bf16x8*)&VtB[(dt * 16 + i) * 32 + ((q ^ tvi) << 3)];
            Oc[0][dt] = __builtin_amdgcn_mfma_f32_16x16x32_bf16(afP[0], bv, Oc[0][dt], 0, 0, 0);
            Oc[1][dt] = __builtin_amdgcn_mfma_f32_16x16x32_bf16(afP[1], bv, Oc[1][dt], 0, 0, 0);
        }
        __builtin_amdgcn_s_setprio(0);
    }

    // one-time l reduction across the 16 i-lanes
    #pragma unroll
    for (int st = 1; st < 16; st <<= 1)
        #pragma unroll
        for (int rg = 0; rg < 2; rg++)
            #pragma unroll
            for (int r = 0; r < 4; r++)
                li[rg][r] += __shfl_xor(li[rg][r], st);

    // epilogue: z = O/l, h = x + z, LayerNorm, store fp32
    float gv[8], bvv[8];
    #pragma unroll
    for (int t = 0; t < 8; t++) { gv[t] = gamma[t * 16 + i]; bvv[t] = beta[t * 16 + i]; }
    #pragma unroll
    for (int rg = 0; rg < 2; rg++)
        for (int r = 0; r < 4; r++) {
            int lg = l0 + w * 32 + rg * 16 + q * 4 + r;
            if (lg >= c) continue;           // uniform across the 16-lane shuffle group
            size_t node = (size_t)(seg + lg);
            float inv = 1.0f / li[rg][r];
            const float* xr = x + node * DIM;
            float h[8], sum = 0.0f, ss = 0.0f;
            #pragma unroll
            for (int t = 0; t < 8; t++) {
                float hv = xr[t * 16 + i] + Oc[rg][t][r] * inv;
                h[t] = hv;
                sum += hv; ss += hv * hv;
            }
            #pragma unroll
            for (int st = 1; st < 16; st <<= 1) {
                sum += __shfl_xor(sum, st);
                ss  += __shfl_xor(ss, st);
            }
            float mu = sum * (1.0f / 128.0f);
            float var = ss * (1.0f / 128.0f) - mu * mu;
            float rstd = rsqrtf(var + 1e-5f);
            float* op = out + node * DIM;
            #pragma unroll
            for (int t = 0; t < 8; t++)
                op[t * 16 + i] = (h[t] - mu) * rstd * gv[t] + bvv[t];
        }
}

extern "C" void kernel_launch(void* const* d_in, const int* in_sizes, int n_in,
                              void* d_out, int out_size, void* d_ws, size_t ws_size,
                              hipStream_t stream) {
    (void)in_sizes; (void)n_in; (void)out_size; (void)ws_size;
    const float* x     = (const float*)d_in[0];
    const float* Wk    = (const float*)d_in[1];
    const float* bk    = (const float*)d_in[2];
    const float* Wq    = (const float*)d_in[3];
    const float* bq    = (const float*)d_in[4];
    const float* Wv    = (const float*)d_in[5];
    const float* bv    = (const float*)d_in[6];
    const float* gamma = (const float*)d_in[7];
    const float* beta  = (const float*)d_in[8];
    const int*   batch = (const int*)d_in[9];
    float* out = (float*)d_out;

    char* ws = (char*)d_ws;
    int*  starts = (int*)(ws + WS_STARTS);
    bf16* Wf  = (bf16*)(ws + WS_WF);
    bf16* Kb  = (bf16*)(ws + WS_KB);
    bf16* Qb  = (bf16*)(ws + WS_QB);
    bf16* Vtb = (bf16*)(ws + WS_VTB);

    seg_starts_kernel<<<1, 512, 0, stream>>>(batch, starts);
    wconv_kernel<<<24, 256, 0, stream>>>(Wk, Wq, Wv, Wf);
    qkv_kernel<<<1024, 512, 0, stream>>>(x, Wf, bk, bq, bv, Kb, Qb, Vtb);
    attn_kernel<<<dim3(NG, 4), 256, 0, stream>>>(x, Kb, Qb, Vtb, gamma, beta, starts, out);
}

// Round 11
// 250.794 us; speedup vs baseline: 1.0290x; 1.0290x over previous
//
#include <hip/hip_runtime.h>
#include <hip/hip_bf16.h>

#define N_NODES 131072
#define DIM 128
#define NG 512

typedef __bf16 bf16;
typedef __attribute__((ext_vector_type(8))) __bf16 bf16x8;
typedef __attribute__((ext_vector_type(4))) float f32x4;

// 1/sqrt(128) * log2(e) — folded into Wk/bk so attention scores exp2 directly
#define KSC 0.12753785006196978f

// workspace layout (bytes)
#define WS_STARTS 0                         // 513 ints
#define WS_WF     8192                      // fragment-ordered W: 3*8*4*64*8 bf16 = 98304 B
#define WS_KB     131072                    // N*128 bf16
#define WS_QB     (131072 + 33554432)
#define WS_VTB    (131072 + 2*33554432)     // Vt[d][n]: 128 x N bf16

__device__ __forceinline__ void gl_lds16(const void* g, void* l) {
    __builtin_amdgcn_global_load_lds(
        (const __attribute__((address_space(1))) unsigned int*)g,
        (__attribute__((address_space(3))) unsigned int*)l, 16, 0, 0);
}

// Merged prep: blocks 0..11 emit Wf (fragment-ordered W, Wk pre-scaled by KSC);
// block 12 computes segment starts. Saves one launch slot vs separate kernels.
__global__ __launch_bounds__(512) void prep_kernel(
        const int* __restrict__ batch, int* __restrict__ starts,
        const float* __restrict__ Wk, const float* __restrict__ Wq,
        const float* __restrict__ Wv, bf16* __restrict__ Wf) {
    if (blockIdx.x < 12) {
        int f = blockIdx.x * 512 + threadIdx.x;  // 0..6143
        int lane = f & 63, ks = (f >> 6) & 3, n0 = (f >> 8) & 7, mat = f >> 11;
        const float* src = (mat == 0) ? Wk : ((mat == 1) ? Wq : Wv);
        float sc = (mat == 0) ? KSC : 1.0f;
        int col = n0 * 16 + (lane & 15);
        int koff = ks * 32 + (lane >> 4) * 8;
        const float* p = src + col * DIM + koff;
        bf16* dst = Wf + (size_t)f * 8;
        #pragma unroll
        for (int j = 0; j < 8; j++) dst[j] = (bf16)(p[j] * sc);
    } else {
        int g = threadIdx.x;                 // 0..511
        int lo = 0, hi = N_NODES;
        while (lo < hi) { int mid = (lo + hi) >> 1; if (batch[mid] < g) lo = mid + 1; else hi = mid; }
        starts[g] = lo;
        if (g == 0) starts[NG] = N_NODES;
    }
}

// QKV projection: out = x @ W^T + b, stored bf16. V stored transposed Vt[d][n].
// R11: 64-row tiles -> 2048 blocks (8 blocks/CU of WORK, was 4 with zero slack).
// qkv is the same latency/granularity disease attn had: its floor is 27us
// (167 MB) but it sits ~3x off with exactly 4 blocks/CU and 8 barriers. attn's
// proven fix was block COUNT (R5: 3 blocks -> -24%), not waves/block (R2, R10
// both null). LDS overlaid to 18432 B (x/C tile union: [64][136] for K/Q phase,
// [128][72] for Vt phase) -> up to 8 resident blocks/CU. No launch-bounds cap
// (R6 lesson: never cap below the accumulator footprint).
__global__ __launch_bounds__(256) void qkv_kernel(
        const float* __restrict__ x, const bf16* __restrict__ Wf,
        const float* __restrict__ bk, const float* __restrict__ bq, const float* __restrict__ bv,
        bf16* __restrict__ Kb, bf16* __restrict__ Qb, bf16* __restrict__ Vtb) {
    __shared__ bf16 buf[9216];               // 18432 B union: [64][136] / [128][72]
    const int tid = threadIdx.x;
    const int w = tid >> 6, lane = tid & 63, q = lane >> 4, i = lane & 15;
    const int r0 = blockIdx.x * 64;

    {   // stage x tile 64x128 (coalesced fp32 loads -> bf16 LDS [64][136])
        #pragma unroll
        for (int it = 0; it < 8; it++) {
            int e = tid * 4 + it * 1024;     // element in 64x128 tile
            int row = e >> 7, col = e & 127;
            float4 u = *(const float4*)(x + (size_t)(r0 + row) * DIM + col);
            bf16 b4[4] = {(bf16)u.x, (bf16)u.y, (bf16)u.z, (bf16)u.w};
            *(ushort4*)&buf[row * 136 + col] = *(ushort4*)b4;
        }
    }
    __syncthreads();

    // A fragments: wave w owns rows r0 + w*16 + i
    bf16x8 af[4];
    #pragma unroll
    for (int ks = 0; ks < 4; ks++)
        af[ks] = *(const bf16x8*)&buf[(w * 16 + i) * 136 + ks * 32 + q * 8];
    __syncthreads();                         // frag reads done before buf reuse

    for (int mat = 0; mat < 3; mat++) {
        const float* bias = (mat == 0) ? bk : ((mat == 1) ? bq : bv);
        const float bscale = (mat == 0) ? KSC : 1.0f;
        for (int n0 = 0; n0 < 8; n0++) {
            int col = n0 * 16 + i;
            float bias_v = bias[col] * bscale;
            f32x4 acc = {0, 0, 0, 0};
            #pragma unroll
            for (int ks = 0; ks < 4; ks++) {
                bf16x8 bw = *(const bf16x8*)(Wf + ((size_t)((mat * 8 + n0) * 4 + ks) * 64 + lane) * 8);
                acc = __builtin_amdgcn_mfma_f32_16x16x32_bf16(af[ks], bw, acc, 0, 0, 0);
            }
            #pragma unroll
            for (int r = 0; r < 4; r++) {
                int rowl = w * 16 + q * 4 + r;
                bf16 hv = (bf16)(acc[r] + bias_v);
                if (mat < 2) buf[rowl * 136 + col] = hv;    // [row][d]
                else         buf[col * 72 + rowl] = hv;     // [d][row]
            }
        }
        __syncthreads();
        if (mat < 2) {   // 64 rows x 256 B: row = tid>>2, 64B quarter each
            int row = tid >> 2, qtr = tid & 3;
            const uint4* src = (const uint4*)(buf + row * 136 + qtr * 32);
            uint4* dst = (uint4*)(((mat == 0) ? Kb : Qb) + (size_t)(r0 + row) * DIM + qtr * 32);
            #pragma unroll
            for (int j = 0; j < 4; j++) dst[j] = src[j];
        } else {         // 128 d-rows x 128 B: d = tid>>1, 64B half each
            int d = tid >> 1, half = tid & 1;
            const uint4* src = (const uint4*)(buf + d * 72 + half * 32);
            uint4* dst = (uint4*)(Vtb + (size_t)d * N_NODES + r0 + half * 32);
            #pragma unroll
            for (int j = 0; j < 4; j++) dst[j] = src[j];
        }
        __syncthreads();
    }
}

// Fused segment attention + residual + LayerNorm.
// FROZEN at R5's measured-best config (82us, reproduced twice). 3-buffer ring,
// 3 blocks/CU, counted vmcnt(4), P overlay, both-sides swizzles. R9 proved the
// grid (~1150 blocks = 4.5 blocks/CU of work) can't exploit >3 resident blocks.
__global__ __launch_bounds__(256, 3) void attn_kernel(
        const float* __restrict__ x,
        const bf16* __restrict__ Kb, const bf16* __restrict__ Qb, const bf16* __restrict__ Vtb,
        const float* __restrict__ gamma, const float* __restrict__ beta,
        const int* __restrict__ starts, float* __restrict__ out) {
    __shared__ bf16 Qs[3][32 * 128];         // 3 x 8192 B; P overlays Qs[cur]
    __shared__ bf16 Vts[3][128 * 32];        // 3 x 8192 B   (total 49152 B -> 3 blocks/CU)

    const int g = blockIdx.x;
    const int seg = starts[g];
    const int c = starts[g + 1] - seg;
    const int l0 = blockIdx.y * 128;
    if (l0 >= c) return;

    const int tid = threadIdx.x;
    const int w = tid >> 6, lane = tid & 63, q = lane >> 4, i = lane & 15;

    const int mstart = seg & ~7;             // 8-aligned -> 16B-aligned staging
    const int nch = (seg - mstart + c + 31) >> 5;   // 32-m chunks (>= 6 since c >= 192)

    // async-stage one 32-m chunk: Q rows (32x128) + Vt rows (128x32), swizzled source.
    // 4 gl_lds16 per wave (2 Q + 2 Vt); LDS dest wave-uniform base + lane*16B (linear).
    auto stage = [&](int buf, int mb) {
        #pragma unroll
        for (int p = 0; p < 2; p++) {        // Q: 1 instr = 4 rows (16 lanes/row)
            int row = w * 8 + p * 4 + (lane >> 4);
            int gr = mb + row; if (gr > N_NODES - 1) gr = N_NODES - 1;
            gl_lds16(Qb + (size_t)gr * DIM + (((lane & 15) ^ (row & 7)) << 3),
                     &Qs[buf][(w * 8 + p * 4) * 128]);
        }
        #pragma unroll
        for (int p = 0; p < 2; p++) {        // Vt: 1 instr = 16 rows (4 lanes/row)
            int d = w * 32 + p * 16 + (lane >> 2);
            int tvd = ((lane >> 2) ^ (lane >> 4)) & 3;       // = (d ^ (d>>2)) & 3
            int mo = mb + (((lane & 3) ^ tvd) << 3);
            if (mo > N_NODES - 8) mo = N_NODES - 8;
            gl_lds16(Vtb + (size_t)d * N_NODES + mo,
                     &Vts[buf][(w * 32 + p * 16) * 32]);
        }
    };

    // K fragments direct from global (row clamped into segment); 32 l-rows per wave
    bf16x8 afK[2][4];
    #pragma unroll
    for (int rg = 0; rg < 2; rg++) {
        int lrow = l0 + w * 32 + rg * 16 + i;
        if (lrow > c - 1) lrow = c - 1;
        const bf16* krow = Kb + (size_t)(seg + lrow) * DIM;
        #pragma unroll
        for (int ks = 0; ks < 4; ks++)
            afK[rg][ks] = *(const bf16x8*)(krow + ks * 32 + q * 8);
    }

    stage(0, mstart);                        // depth-2 pipeline prologue
    if (nch > 1) stage(1, mstart + 32);

    float li[2][4] = {{0,0,0,0},{0,0,0,0}};
    f32x4 Oc[2][8];
    #pragma unroll
    for (int rg = 0; rg < 2; rg++)
        #pragma unroll
        for (int t = 0; t < 8; t++) Oc[rg][t] = (f32x4){0,0,0,0};

    const int f7 = i & 7;                    // Q-read swizzle term (= row&7)
    const int tvi = (i ^ (i >> 2)) & 3;      // Vt/P read swizzle term

    for (int mc = 0; mc < nch; mc++) {
        const int cur = mc % 3;
        const int mbase = mstart + (mc << 5);
        // counted wait: retire chunk mc's 4 DMAs; chunk mc+1's 4 stay in flight
        if (mc + 1 < nch) asm volatile("s_waitcnt vmcnt(4)" ::: "memory");
        else              asm volatile("s_waitcnt vmcnt(0)" ::: "memory");
        __builtin_amdgcn_s_barrier();
        __builtin_amdgcn_sched_barrier(0);
        // buf (mc+2)%3 was fully consumed in iteration mc-1 (readers passed this barrier)
        if (mc + 2 < nch) stage((mc + 2) % 3, mbase + 64);

        const bf16* QsB = Qs[cur];
        const bf16* VtB = Vts[cur];
        bf16* Pw = &Qs[cur][w * 1024];       // wave-private 32x32 P slice (overlay)

        // S = K * Q^T (32 l-rows x 32 m-cols per wave): 8 bq reads feed 16 MFMAs
        f32x4 s[2][2];
        __builtin_amdgcn_s_setprio(1);
        #pragma unroll
        for (int ti = 0; ti < 2; ti++) {
            f32x4 a0 = {0,0,0,0}, a1 = {0,0,0,0};
            #pragma unroll
            for (int ks = 0; ks < 4; ks++) {
                bf16x8 bq = *(const bf16x8*)&QsB[(ti * 16 + i) * 128 + (((ks * 4 + q) ^ f7) << 3)];
                a0 = __builtin_amdgcn_mfma_f32_16x16x32_bf16(afK[0][ks], bq, a0, 0, 0, 0);
                a1 = __builtin_amdgcn_mfma_f32_16x16x32_bf16(afK[1][ks], bq, a1, 0, 0, 0);
            }
            s[0][ti] = a0; s[1][ti] = a1;
        }
        __builtin_amdgcn_s_setprio(0);
        if (mc == 0 || mc == nch - 1) {      // only edge chunks can have invalid m
            #pragma unroll
            for (int ti = 0; ti < 2; ti++) {
                int mg = mbase + ti * 16 + i;
                bool valid = (mg >= seg) && (mg < seg + c);
                if (!valid) {
                    s[0][ti] = (f32x4){-1.0e30f, -1.0e30f, -1.0e30f, -1.0e30f};
                    s[1][ti] = s[0][ti];
                }
            }
        }
        // p = exp2(s) in registers; accumulate l per-lane
        #pragma unroll
        for (int rg = 0; rg < 2; rg++)
            #pragma unroll
            for (int ti = 0; ti < 2; ti++)
                #pragma unroll
                for (int r = 0; r < 4; r++) {
                    float pv = exp2f(s[rg][ti][r]);
                    li[rg][r] += pv;
                    s[rg][ti][r] = pv;
                }

        // raw barrier: all waves' Qs[cur] reads retired; DMA (vmcnt) stays in flight
        asm volatile("s_waitcnt lgkmcnt(0)" ::: "memory");
        __builtin_amdgcn_s_barrier();
        __builtin_amdgcn_sched_barrier(0);

        // write P into overlay (rows = wave's 32 l-rows, cols = 32 m), swizzled:
        // slot = colgranule ^ (q^r)   [q^r == (row ^ row>>2)&3 for row=rg*16+q*4+r]
        #pragma unroll
        for (int rg = 0; rg < 2; rg++)
            #pragma unroll
            for (int ti = 0; ti < 2; ti++)
                #pragma unroll
                for (int r = 0; r < 4; r++) {
                    int rowl = rg * 16 + q * 4 + r;
                    int slot = (ti * 2 + (i >> 3)) ^ (q ^ r);
                    Pw[rowl * 32 + slot * 8 + f7] = (bf16)s[rg][ti][r];
                }

        // read P as A-fragments (same-wave LDS FIFO: no barrier needed)
        bf16x8 afP[2];
        #pragma unroll
        for (int rg = 0; rg < 2; rg++)
            afP[rg] = *(const bf16x8*)&Pw[(rg * 16 + i) * 32 + ((q ^ tvi) << 3)];

        // O += P * Vt: 8 bv reads feed 16 MFMAs
        __builtin_amdgcn_s_setprio(1);
        #pragma unroll
        for (int dt = 0; dt < 8; dt++) {
            bf16x8 bv = *(const bf16x8*)&VtB[(dt * 16 + i) * 32 + ((q ^ tvi) << 3)];
            Oc[0][dt] = __builtin_amdgcn_mfma_f32_16x16x32_bf16(afP[0], bv, Oc[0][dt], 0, 0, 0);
            Oc[1][dt] = __builtin_amdgcn_mfma_f32_16x16x32_bf16(afP[1], bv, Oc[1][dt], 0, 0, 0);
        }
        __builtin_amdgcn_s_setprio(0);
    }

    // one-time l reduction across the 16 i-lanes
    #pragma unroll
    for (int st = 1; st < 16; st <<= 1)
        #pragma unroll
        for (int rg = 0; rg < 2; rg++)
            #pragma unroll
            for (int r = 0; r < 4; r++)
                li[rg][r] += __shfl_xor(li[rg][r], st);

    // epilogue: z = O/l, h = x + z, LayerNorm, store fp32
    float gv[8], bvv[8];
    #pragma unroll
    for (int t = 0; t < 8; t++) { gv[t] = gamma[t * 16 + i]; bvv[t] = beta[t * 16 + i]; }
    #pragma unroll
    for (int rg = 0; rg < 2; rg++)
        for (int r = 0; r < 4; r++) {
            int lg = l0 + w * 32 + rg * 16 + q * 4 + r;
            if (lg >= c) continue;           // uniform across the 16-lane shuffle group
            size_t node = (size_t)(seg + lg);
            float inv = 1.0f / li[rg][r];
            const float* xr = x + node * DIM;
            float h[8], sum = 0.0f, ss = 0.0f;
            #pragma unroll
            for (int t = 0; t < 8; t++) {
                float hv = xr[t * 16 + i] + Oc[rg][t][r] * inv;
                h[t] = hv;
                sum += hv; ss += hv * hv;
            }
            #pragma unroll
            for (int st = 1; st < 16; st <<= 1) {
                sum += __shfl_xor(sum, st);
                ss  += __shfl_xor(ss, st);
            }
            float mu = sum * (1.0f / 128.0f);
            float var = ss * (1.0f / 128.0f) - mu * mu;
            float rstd = rsqrtf(var + 1e-5f);
            float* op = out + node * DIM;
            #pragma unroll
            for (int t = 0; t < 8; t++)
                op[t * 16 + i] = (h[t] - mu) * rstd * gv[t] + bvv[t];
        }
}

extern "C" void kernel_launch(void* const* d_in, const int* in_sizes, int n_in,
                              void* d_out, int out_size, void* d_ws, size_t ws_size,
                              hipStream_t stream) {
    (void)in_sizes; (void)n_in; (void)out_size; (void)ws_size;
    const float* x     = (const float*)d_in[0];
    const float* Wk    = (const float*)d_in[1];
    const float* bk    = (const float*)d_in[2];
    const float* Wq    = (const float*)d_in[3];
    const float* bq    = (const float*)d_in[4];
    const float* Wv    = (const float*)d_in[5];
    const float* bv    = (const float*)d_in[6];
    const float* gamma = (const float*)d_in[7];
    const float* beta  = (const float*)d_in[8];
    const int*   batch = (const int*)d_in[9];
    float* out = (float*)d_out;

    char* ws = (char*)d_ws;
    int*  starts = (int*)(ws + WS_STARTS);
    bf16* Wf  = (bf16*)(ws + WS_WF);
    bf16* Kb  = (bf16*)(ws + WS_KB);
    bf16* Qb  = (bf16*)(ws + WS_QB);
    bf16* Vtb = (bf16*)(ws + WS_VTB);

    prep_kernel<<<13, 512, 0, stream>>>(batch, starts, Wk, Wq, Wv, Wf);
    qkv_kernel<<<2048, 256, 0, stream>>>(x, Wf, bk, bq, bv, Kb, Qb, Vtb);
    attn_kernel<<<dim3(NG, 4), 256, 0, stream>>>(x, Kb, Qb, Vtb, gamma, beta, starts, out);
}